// Round 11
// baseline (55.953 us; speedup 1.0000x reference)
//
#include <hip/hip_runtime.h>
#include <stdint.h>
#include <math.h>

// Problem constants (fixed by the reference)
#define BATCH 8
#define HH 2048
#define WW 2048
#define R 16                           // rows per chunk (vertical halo ratio 20/16)
#define NSTRIPS (HH / R)               // 128 full-width strips per image
#define HALF_W 1024                    // kernel-1 chunk width (2 halves per strip)
#define NBLK1 (BATCH * NSTRIPS * 2)    // 2048 kernel-1 blocks -> 8 waves/SIMD
#define NBLK2 (BATCH * NSTRIPS)        // 1024 kernel-2 blocks (full strips)
#define BLK_WORDS (R * WW / 32)        // 1024 mask dwords per full strip
#define MAXK 2000000
#define TAIL_I4 (MAXK / 4)             // 500000 int4 slots per output plane
#define TAIL_PER_BLK ((TAIL_I4 + NBLK2 - 1) / NBLK2)  // 489

// ---------------- Kernel 1: 5x5 local-max mask + per-half-chunk count ------
// One block per 16x1024 half-chunk; 2048 blocks = 8 blocks/CU = 8 waves/SIMD
// (double round-8's occupancy at identical HBM bytes: vertical ratio stays
// 20/16, horizontal halo is cache-hits only). Thread owns 4 consecutive cols
// (float4 load) + 2-col halo each side (float2 loads, same cachelines).
// Mask bytes (global, row-major flat) packed from two threads' nibbles.
__global__ __launch_bounds__(256, 8) void nms_mask(const float* __restrict__ scores,
                                                   uint8_t* __restrict__ maskbytes,
                                                   int* __restrict__ counts) {
    const int bid  = (int)blockIdx.x;         // = b*256 + strip*2 + half
    const int tid  = threadIdx.x;
    const int lane = tid & 63;
    const int wv   = tid >> 6;

    const int b     = bid >> 8;
    const int rem   = bid & 255;
    const int strip = rem >> 1;
    const int half  = rem & 1;
    const int h0    = strip * R;
    const int c0    = half * HALF_W + tid * 4;   // first owned column
    const float* colp = scores + (size_t)b * HH * WW + c0;
    const bool has_l = (c0 != 0);
    const bool has_r = (c0 != WW - 4);

    float win[5][8];  // columns c0-2 .. c0+5

#define LOAD_ROW(PH, hrow)                                                    \
    do {                                                                      \
        const int h_ = (hrow);                                                \
        if ((unsigned)h_ < (unsigned)HH) {                                    \
            const float* p_ = colp + (size_t)h_ * WW;                         \
            float4 a_ = *(const float4*)(p_);                                 \
            win[PH][2] = a_.x; win[PH][3] = a_.y;                             \
            win[PH][4] = a_.z; win[PH][5] = a_.w;                             \
            if (has_l) {                                                      \
                float2 hl_ = *(const float2*)(p_ - 2);                        \
                win[PH][0] = hl_.x; win[PH][1] = hl_.y;                       \
            } else { win[PH][0] = -INFINITY; win[PH][1] = -INFINITY; }        \
            if (has_r) {                                                      \
                float2 hr_ = *(const float2*)(p_ + 4);                        \
                win[PH][6] = hr_.x; win[PH][7] = hr_.y;                       \
            } else { win[PH][6] = -INFINITY; win[PH][7] = -INFINITY; }        \
        } else {                                                              \
            _Pragma("unroll")                                                 \
            for (int k_ = 0; k_ < 8; ++k_) win[PH][k_] = -INFINITY;           \
        }                                                                     \
    } while (0)

    LOAD_ROW(0, h0 - 2);
    LOAD_ROW(1, h0 - 1);
    LOAD_ROW(2, h0 + 0);
    LOAD_ROW(3, h0 + 1);

    int pc = 0;
    // byte address of this thread's (shared) output byte, row h0
    size_t outbyte = (((size_t)(b * HH + h0) * WW) >> 3) + (size_t)(half * 128 + (tid >> 1));
    const bool store_lane = ((lane & 1) == 0);

#pragma unroll
    for (int i = 0; i < R; ++i) {
        LOAD_ROW((4 + i) % 5, h0 + 2 + i);
        const int CEN = (2 + i) % 5;

        // vertical 5-max per column
        float v[8];
#pragma unroll
        for (int k = 0; k < 8; ++k)
            v[k] = fmaxf(fmaxf(fmaxf(win[0][k], win[1][k]),
                               fmaxf(win[2][k], win[3][k])), win[4][k]);
        // horizontal pair maxes
        float p[7];
#pragma unroll
        for (int k = 0; k < 7; ++k) p[k] = fmaxf(v[k], v[k + 1]);

        uint32_t nib = 0;
#pragma unroll
        for (int j = 0; j < 4; ++j) {
            const float hm = fmaxf(fmaxf(p[j], p[j + 2]), v[j + 4]);
            const float s  = win[CEN][j + 2];
            if ((s == hm) && (s > 0.0f)) nib |= (1u << j);
        }
        pc += __popc(nib);

        // pack two adjacent threads' nibbles into one byte; even lane stores
        const uint32_t other = __shfl_down(nib, 1, 64);
        if (store_lane) maskbytes[outbyte] = (uint8_t)(nib | (other << 4));
        outbyte += WW / 8;
    }
#undef LOAD_ROW

    // per-half-chunk count
#pragma unroll
    for (int d = 32; d >= 1; d >>= 1) pc += __shfl_down(pc, d, 64);
    __shared__ int wsum[4];
    if (lane == 0) wsum[wv] = pc;
    __syncthreads();
    if (tid == 0) counts[bid] = wsum[0] + wsum[1] + wsum[2] + wsum[3];
}

// ---------------- Kernel 2: ordered compaction + tail fill -----------------
// One block per full 16x2048 strip (contiguous flat range). Reads the 8 KB
// counts array (L2-hot): masked reduce -> exclusive prefix (counts[j], j <
// 2*chunk, since each strip = 2 half-chunks); full reduce -> grand total for
// the -1 tail. All writes disjoint from the scatter.
__global__ __launch_bounds__(256) void compact(const uint32_t* __restrict__ bitmask,
                                               const int* __restrict__ counts,
                                               int* __restrict__ out_h,
                                               int* __restrict__ out_w) {
    const int chunk = (int)blockIdx.x;           // 0..NBLK2-1, = b*NSTRIPS+strip
    const int tid   = threadIdx.x;
    const int lane  = tid & 63, wv = tid >> 6;
    const int lim   = 2 * chunk;                 // half-chunks before this strip

    // counts[8t .. 8t+7] per thread
    const uint4 ca = ((const uint4*)counts)[2 * tid];
    const uint4 cb = ((const uint4*)counts)[2 * tid + 1];
    const int i0 = tid * 8;
    int contrib = 0, full = 0;
    {
        const uint32_t cv[8] = {ca.x, ca.y, ca.z, ca.w, cb.x, cb.y, cb.z, cb.w};
#pragma unroll
        for (int j = 0; j < 8; ++j) {
            full += (int)cv[j];
            contrib += (i0 + j < lim) ? (int)cv[j] : 0;
        }
    }

    int rA = contrib, rB = full;
#pragma unroll
    for (int d = 32; d >= 1; d >>= 1) {
        rA += __shfl_down(rA, d, 64);
        rB += __shfl_down(rB, d, 64);
    }
    __shared__ int wsA[4], wsB[4], wscan[4];
    if (lane == 0) { wsA[wv] = rA; wsB[wv] = rB; }

    // this strip's mask: 1024 dwords, uint4 per thread
    const uint4 m = ((const uint4*)(bitmask + (size_t)chunk * BLK_WORDS))[tid];
    const int pc = __popc(m.x) + __popc(m.y) + __popc(m.z) + __popc(m.w);

    int incl = pc;
#pragma unroll
    for (int d = 1; d < 64; d <<= 1) {
        int n = __shfl_up(incl, d, 64);
        if (lane >= d) incl += n;
    }
    if (lane == 63) wscan[wv] = incl;
    __syncthreads();

    const int chunk_base = wsA[0] + wsA[1] + wsA[2] + wsA[3];
    int total = wsB[0] + wsB[1] + wsB[2] + wsB[3];
    if (total > MAXK) total = MAXK;
    int wbase = 0;
    for (int i = 0; i < wv; ++i) wbase += wscan[i];

    const int h0 = (chunk & (NSTRIPS - 1)) * R;
    int off = chunk_base + wbase + (incl - pc);

    // ordered scatter
    uint32_t words[4] = {m.x, m.y, m.z, m.w};
    const uint32_t local0 = (uint32_t)tid * 128u;  // tid*4 dwords * 32 bits
#pragma unroll
    for (int wj = 0; wj < 4; ++wj) {
        uint32_t mm = words[wj];
        const uint32_t lb = local0 + (uint32_t)wj * 32u;
        while (mm) {
            const int bit = __ffs(mm) - 1;
            mm &= mm - 1;
            const uint32_t L = lb + (uint32_t)bit;  // bit index within strip
            if (off < MAXK) {
                out_h[off] = h0 + (int)(L >> 11);
                out_w[off] = (int)(L & 2047u);
            }
            ++off;
        }
    }

    // -1 tail fill: this block's slice of [total, MAXK) in both planes
    const int i4base = chunk * TAIL_PER_BLK;
    for (int t = tid; t < TAIL_PER_BLK; t += 256) {
        const int i4 = i4base + t;
        if (i4 >= TAIL_I4) break;
        const int base = i4 * 4;
        if (base + 4 <= total) continue;  // fully covered by scatter
        if (base >= total) {
            const int4 neg = make_int4(-1, -1, -1, -1);
            *(int4*)(out_h + base) = neg;
            *(int4*)(out_w + base) = neg;
        } else {
#pragma unroll
            for (int j = 0; j < 4; ++j) {
                const int idx = base + j;
                if (idx >= total) { out_h[idx] = -1; out_w[idx] = -1; }
            }
        }
    }
}

extern "C" void kernel_launch(void* const* d_in, const int* in_sizes, int n_in,
                              void* d_out, int out_size, void* d_ws, size_t ws_size,
                              hipStream_t stream) {
    const float* scores = (const float*)d_in[0];
    int* out = (int*)d_out;

    uint32_t* bitmask = (uint32_t*)d_ws;                                // 4 MB
    int* counts = (int*)((char*)d_ws + (size_t)NBLK2 * BLK_WORDS * 4);  // NBLK1 ints

    nms_mask<<<NBLK1, 256, 0, stream>>>(scores, (uint8_t*)bitmask, counts);
    compact<<<NBLK2, 256, 0, stream>>>(bitmask, counts, out, out + MAXK);
}

// Round 12
// 45.920 us; speedup vs baseline: 1.2185x; 1.2185x over previous
//
#include <hip/hip_runtime.h>
#include <stdint.h>
#include <math.h>

// Problem constants (fixed by the reference)
#define BATCH 8
#define HH 2048
#define WW 2048
#define R 16                           // rows per chunk (vertical halo ratio 20/16)
#define NSTRIPS (HH / R)               // 128 full-width strips per image
#define HALF_W 1024                    // kernel-1 chunk width (2 halves per strip)
#define NBLK1 (BATCH * NSTRIPS * 2)    // 2048 kernel-1 blocks -> 8 blocks/CU
#define NBLK2 (BATCH * NSTRIPS)        // 1024 kernel-2 blocks (full strips)
#define BLK_WORDS (R * WW / 32)        // 1024 mask dwords per full strip
#define MAXK 2000000
#define TAIL_I4 (MAXK / 4)             // 500000 int4 slots per output plane
#define TAIL_PER_BLK ((TAIL_I4 + NBLK2 - 1) / NBLK2)  // 489

// ---------------- Kernel 1: 5x5 local-max mask + per-half-chunk count ------
// One block per 16x1024 half-chunk; 2048 blocks = 8 blocks/CU. NO min-waves
// clause: round 11 proved __launch_bounds__(256,8) caps VGPR at 32 and spills
// the 40-float rolling window to scratch (WRITE_SIZE 4->35 MB, 2.5x slower).
// Natural allocation (~44-56 VGPR) still permits 8 waves/SIMD.
__global__ __launch_bounds__(256) void nms_mask(const float* __restrict__ scores,
                                                uint8_t* __restrict__ maskbytes,
                                                int* __restrict__ counts) {
    const int bid  = (int)blockIdx.x;         // = b*256 + strip*2 + half
    const int tid  = threadIdx.x;
    const int lane = tid & 63;
    const int wv   = tid >> 6;

    const int b     = bid >> 8;
    const int rem   = bid & 255;
    const int strip = rem >> 1;
    const int half  = rem & 1;
    const int h0    = strip * R;
    const int c0    = half * HALF_W + tid * 4;   // first owned column
    const float* colp = scores + (size_t)b * HH * WW + c0;
    const bool has_l = (c0 != 0);
    const bool has_r = (c0 != WW - 4);

    float win[5][8];  // columns c0-2 .. c0+5

#define LOAD_ROW(PH, hrow)                                                    \
    do {                                                                      \
        const int h_ = (hrow);                                                \
        if ((unsigned)h_ < (unsigned)HH) {                                    \
            const float* p_ = colp + (size_t)h_ * WW;                         \
            float4 a_ = *(const float4*)(p_);                                 \
            win[PH][2] = a_.x; win[PH][3] = a_.y;                             \
            win[PH][4] = a_.z; win[PH][5] = a_.w;                             \
            if (has_l) {                                                      \
                float2 hl_ = *(const float2*)(p_ - 2);                        \
                win[PH][0] = hl_.x; win[PH][1] = hl_.y;                       \
            } else { win[PH][0] = -INFINITY; win[PH][1] = -INFINITY; }        \
            if (has_r) {                                                      \
                float2 hr_ = *(const float2*)(p_ + 4);                        \
                win[PH][6] = hr_.x; win[PH][7] = hr_.y;                       \
            } else { win[PH][6] = -INFINITY; win[PH][7] = -INFINITY; }        \
        } else {                                                              \
            _Pragma("unroll")                                                 \
            for (int k_ = 0; k_ < 8; ++k_) win[PH][k_] = -INFINITY;           \
        }                                                                     \
    } while (0)

    LOAD_ROW(0, h0 - 2);
    LOAD_ROW(1, h0 - 1);
    LOAD_ROW(2, h0 + 0);
    LOAD_ROW(3, h0 + 1);

    int pc = 0;
    // byte address of this thread's (shared) output byte, row h0
    size_t outbyte = (((size_t)(b * HH + h0) * WW) >> 3) + (size_t)(half * 128 + (tid >> 1));
    const bool store_lane = ((lane & 1) == 0);

#pragma unroll
    for (int i = 0; i < R; ++i) {
        LOAD_ROW((4 + i) % 5, h0 + 2 + i);
        const int CEN = (2 + i) % 5;

        // vertical 5-max per column
        float v[8];
#pragma unroll
        for (int k = 0; k < 8; ++k)
            v[k] = fmaxf(fmaxf(fmaxf(win[0][k], win[1][k]),
                               fmaxf(win[2][k], win[3][k])), win[4][k]);
        // horizontal pair maxes
        float p[7];
#pragma unroll
        for (int k = 0; k < 7; ++k) p[k] = fmaxf(v[k], v[k + 1]);

        uint32_t nib = 0;
#pragma unroll
        for (int j = 0; j < 4; ++j) {
            const float hm = fmaxf(fmaxf(p[j], p[j + 2]), v[j + 4]);
            const float s  = win[CEN][j + 2];
            if ((s == hm) && (s > 0.0f)) nib |= (1u << j);
        }
        pc += __popc(nib);

        // pack two adjacent threads' nibbles into one byte; even lane stores
        const uint32_t other = __shfl_down(nib, 1, 64);
        if (store_lane) maskbytes[outbyte] = (uint8_t)(nib | (other << 4));
        outbyte += WW / 8;
    }
#undef LOAD_ROW

    // per-half-chunk count
#pragma unroll
    for (int d = 32; d >= 1; d >>= 1) pc += __shfl_down(pc, d, 64);
    __shared__ int wsum[4];
    if (lane == 0) wsum[wv] = pc;
    __syncthreads();
    if (tid == 0) counts[bid] = wsum[0] + wsum[1] + wsum[2] + wsum[3];
}

// ---------------- Kernel 2: ordered compaction + tail fill -----------------
// One block per full 16x2048 strip (contiguous flat range). Reads the 8 KB
// counts array (L2-hot): masked reduce -> exclusive prefix (counts[j], j <
// 2*chunk, since each strip = 2 half-chunks); full reduce -> grand total for
// the -1 tail. All writes disjoint from the scatter.
__global__ __launch_bounds__(256) void compact(const uint32_t* __restrict__ bitmask,
                                               const int* __restrict__ counts,
                                               int* __restrict__ out_h,
                                               int* __restrict__ out_w) {
    const int chunk = (int)blockIdx.x;           // 0..NBLK2-1, = b*NSTRIPS+strip
    const int tid   = threadIdx.x;
    const int lane  = tid & 63, wv = tid >> 6;
    const int lim   = 2 * chunk;                 // half-chunks before this strip

    // counts[8t .. 8t+7] per thread
    const uint4 ca = ((const uint4*)counts)[2 * tid];
    const uint4 cb = ((const uint4*)counts)[2 * tid + 1];
    const int i0 = tid * 8;
    int contrib = 0, full = 0;
    {
        const uint32_t cv[8] = {ca.x, ca.y, ca.z, ca.w, cb.x, cb.y, cb.z, cb.w};
#pragma unroll
        for (int j = 0; j < 8; ++j) {
            full += (int)cv[j];
            contrib += (i0 + j < lim) ? (int)cv[j] : 0;
        }
    }

    int rA = contrib, rB = full;
#pragma unroll
    for (int d = 32; d >= 1; d >>= 1) {
        rA += __shfl_down(rA, d, 64);
        rB += __shfl_down(rB, d, 64);
    }
    __shared__ int wsA[4], wsB[4], wscan[4];
    if (lane == 0) { wsA[wv] = rA; wsB[wv] = rB; }

    // this strip's mask: 1024 dwords, uint4 per thread
    const uint4 m = ((const uint4*)(bitmask + (size_t)chunk * BLK_WORDS))[tid];
    const int pc = __popc(m.x) + __popc(m.y) + __popc(m.z) + __popc(m.w);

    int incl = pc;
#pragma unroll
    for (int d = 1; d < 64; d <<= 1) {
        int n = __shfl_up(incl, d, 64);
        if (lane >= d) incl += n;
    }
    if (lane == 63) wscan[wv] = incl;
    __syncthreads();

    const int chunk_base = wsA[0] + wsA[1] + wsA[2] + wsA[3];
    int total = wsB[0] + wsB[1] + wsB[2] + wsB[3];
    if (total > MAXK) total = MAXK;
    int wbase = 0;
    for (int i = 0; i < wv; ++i) wbase += wscan[i];

    const int h0 = (chunk & (NSTRIPS - 1)) * R;
    int off = chunk_base + wbase + (incl - pc);

    // ordered scatter
    uint32_t words[4] = {m.x, m.y, m.z, m.w};
    const uint32_t local0 = (uint32_t)tid * 128u;  // tid*4 dwords * 32 bits
#pragma unroll
    for (int wj = 0; wj < 4; ++wj) {
        uint32_t mm = words[wj];
        const uint32_t lb = local0 + (uint32_t)wj * 32u;
        while (mm) {
            const int bit = __ffs(mm) - 1;
            mm &= mm - 1;
            const uint32_t L = lb + (uint32_t)bit;  // bit index within strip
            if (off < MAXK) {
                out_h[off] = h0 + (int)(L >> 11);
                out_w[off] = (int)(L & 2047u);
            }
            ++off;
        }
    }

    // -1 tail fill: this block's slice of [total, MAXK) in both planes
    const int i4base = chunk * TAIL_PER_BLK;
    for (int t = tid; t < TAIL_PER_BLK; t += 256) {
        const int i4 = i4base + t;
        if (i4 >= TAIL_I4) break;
        const int base = i4 * 4;
        if (base + 4 <= total) continue;  // fully covered by scatter
        if (base >= total) {
            const int4 neg = make_int4(-1, -1, -1, -1);
            *(int4*)(out_h + base) = neg;
            *(int4*)(out_w + base) = neg;
        } else {
#pragma unroll
            for (int j = 0; j < 4; ++j) {
                const int idx = base + j;
                if (idx >= total) { out_h[idx] = -1; out_w[idx] = -1; }
            }
        }
    }
}

extern "C" void kernel_launch(void* const* d_in, const int* in_sizes, int n_in,
                              void* d_out, int out_size, void* d_ws, size_t ws_size,
                              hipStream_t stream) {
    const float* scores = (const float*)d_in[0];
    int* out = (int*)d_out;

    uint32_t* bitmask = (uint32_t*)d_ws;                                // 4 MB
    int* counts = (int*)((char*)d_ws + (size_t)NBLK2 * BLK_WORDS * 4);  // NBLK1 ints

    nms_mask<<<NBLK1, 256, 0, stream>>>(scores, (uint8_t*)bitmask, counts);
    compact<<<NBLK2, 256, 0, stream>>>(bitmask, counts, out, out + MAXK);
}